// Round 18
// baseline (297.631 us; speedup 1.0000x reference)
//
#include <hip/hip_runtime.h>
#include <hip/hip_bf16.h>

typedef unsigned short u16;
typedef unsigned int   u32;
typedef __attribute__((ext_vector_type(8))) __bf16 bf16x8;
typedef __attribute__((ext_vector_type(4))) float  f32x4;
typedef __attribute__((ext_vector_type(8))) u16    u16x8;
typedef __attribute__((ext_vector_type(4))) u16    u16x4;
typedef __attribute__((ext_vector_type(2))) u32    u32x2;
typedef __attribute__((ext_vector_type(4))) u32    u32x4;

#define S_LEN 2048
#define DMODEL 4096
#define NH 64
#define NKV 4
#define HD 64

__device__ __forceinline__ u16 f2bf(float f) {
  u32 u = __builtin_bit_cast(u32, f);
  u32 r = (u + 0x7FFFu + ((u >> 16) & 1u)) >> 16;
  return (u16)r;
}
__device__ __forceinline__ u16 bfc(float f) {
  return __builtin_bit_cast(u16, (__bf16)f);
}
__device__ __forceinline__ u32 pk2(float lo, float hi) {
  return (u32)bfc(lo) | ((u32)bfc(hi) << 16);
}
__device__ __forceinline__ float bf2f(u16 u) {
  return __builtin_bit_cast(float, (u32)u << 16);
}
__device__ __forceinline__ float ex2(float x) { return __builtin_amdgcn_exp2f(x); }

__device__ __forceinline__ void gll16(const void* g, void* l) {
  __builtin_amdgcn_global_load_lds(
      (__attribute__((address_space(1))) void*)g,
      (__attribute__((address_space(3))) void*)l, 16, 0, 0);
}

// ---------------- elementwise converts ----------------
__global__ __launch_bounds__(256) void cvt_f32_bf16_v4(const float* __restrict__ in,
                                                       u16* __restrict__ out) {
  const int i = blockIdx.x * 256 + threadIdx.x;
  float4 f = ((const float4*)in)[i];
  u16x4 u = { f2bf(f.x), f2bf(f.y), f2bf(f.z), f2bf(f.w) };
  *(u16x4*)&out[(size_t)i * 4] = u;
}

// transpose-convert: in fp32 R x C (row stride istride) -> out bf16 C x R
__global__ __launch_bounds__(256) void tconvs(const float* __restrict__ in, int istride,
                                              u16* __restrict__ out, int R, int C) {
  __shared__ __align__(16) float tile[32][36];
  const int nc = C >> 5;
  const int cb = blockIdx.x % nc, rb = blockIdx.x / nc;
  const int r = threadIdx.x >> 3, c4 = (threadIdx.x & 7) << 2;
  float4 v = *(const float4*)&in[(size_t)(rb * 32 + r) * istride + cb * 32 + c4];
  *(float4*)&tile[r][c4] = v;
  __syncthreads();
  u32x2 pr;
  pr[0] = pk2(tile[c4 + 0][r], tile[c4 + 1][r]);
  pr[1] = pk2(tile[c4 + 2][r], tile[c4 + 3][r]);
  *(u32x2*)&out[(size_t)(cb * 32 + r) * R + rb * 32 + c4] = pr;
}

// transpose-convert summing 4 fp32 partial slices (slice stride pstr elems)
__global__ __launch_bounds__(256) void tconvs4(const float* __restrict__ in, int istride,
                                               size_t pstr,
                                               u16* __restrict__ out, int R, int C) {
  __shared__ __align__(16) float tile[32][36];
  const int nc = C >> 5;
  const int cb = blockIdx.x % nc, rb = blockIdx.x / nc;
  const int r = threadIdx.x >> 3, c4 = (threadIdx.x & 7) << 2;
  const size_t idx = (size_t)(rb * 32 + r) * istride + cb * 32 + c4;
  float4 v = *(const float4*)&in[idx];
#pragma unroll
  for (int j = 1; j < 4; ++j) {
    float4 u = *(const float4*)&in[idx + j * pstr];
    v.x += u.x; v.y += u.y; v.z += u.z; v.w += u.w;
  }
  *(float4*)&tile[r][c4] = v;
  __syncthreads();
  u32x2 pr;
  pr[0] = pk2(tile[c4 + 0][r], tile[c4 + 1][r]);
  pr[1] = pk2(tile[c4 + 2][r], tile[c4 + 3][r]);
  *(u32x2*)&out[(size_t)(cb * 32 + r) * R + rb * 32 + c4] = pr;
}

// ---------------- RMSNorm + RoPE, fp32 4-partial input (K path) ------------
__global__ __launch_bounds__(256) void norm_rope_k4(const float* __restrict__ in,
                                                    size_t pstr,
                                                    int in_stride, int nheads,
                                                    const float* __restrict__ nw,
                                                    const float* __restrict__ cosT,
                                                    const float* __restrict__ sinT,
                                                    u16* __restrict__ outp, int out_stride,
                                                    float oscale) {
  const int wid = blockIdx.x * 4 + (threadIdx.x >> 6);
  const int l = threadIdx.x & 63;
  const int s = wid / nheads, h = wid - s * nheads;
  const size_t idx = (size_t)s * in_stride + h * 64 + l;
  float v = in[idx];
#pragma unroll
  for (int j = 1; j < 4; ++j) v += in[idx + j * pstr];
  float sq = v * v;
#pragma unroll
  for (int off = 32; off; off >>= 1) sq += __shfl_xor(sq, off, 64);
  const float rr = rsqrtf(sq * (1.f / 64.f) + 1e-5f);
  const float vn = v * rr * nw[l];
  const float p = __shfl_xor(vn, 1, 64);
  const int i2 = l >> 1;
  const float c = cosT[(size_t)s * 32 + i2];
  const float sn = sinT[(size_t)s * 32 + i2];
  const float o = ((l & 1) ? fmaf(p, sn, vn * c) : fmaf(-p, sn, vn * c)) * oscale;
  outp[(size_t)s * out_stride + h * 64 + l] = f2bf(o);
}

// ---------------- KV projection: 128x128 tiles, split-K=4 (256 blocks) --------
__global__ __launch_bounds__(256) void gemm_kv(const u16* __restrict__ A,
                                               const u16* __restrict__ Bt,
                                               float* __restrict__ C, size_t pstr,
                                               int M, int N, int K) {
  __shared__ __align__(16) u16 As[128 * 32];
  __shared__ __align__(16) u16 Bs[128 * 32];
  int bid = blockIdx.x;
  const int cpx = gridDim.x >> 3;
  bid = (bid & 7) * cpx + (bid >> 3);
  const int nbn = N >> 7;
  const int pertile = (M >> 7) * nbn;
  const int sl = bid / pertile;
  const int rem = bid - sl * pertile;
  const int bm = rem / nbn, bn = rem % nbn;
  const int m0 = bm << 7, n0 = bn << 7;
  const int tid = threadIdx.x;
  const int w = tid >> 6, l = tid & 63;
  const int wr = w >> 1, wc = w & 1;
  f32x4 acc[4][4] = {};

  const int Kq = K >> 2;
  const int kbase = sl * Kq;

  const char* Ag = (const char*)A +
      ((size_t)(m0 + w * 32 + (l >> 2)) * K + kbase + (l & 3) * 8) * 2;
  const char* Bg = (const char*)Bt +
      ((size_t)(n0 + w * 32 + (l >> 2)) * K + kbase + (l & 3) * 8) * 2;
  char* Al = (char*)As + (w * 32) * 64;
  char* Bl = (char*)Bs + (w * 32) * 64;
  const size_t rowadv = (size_t)16 * K * 2;

  for (int k0 = 0; k0 < Kq; k0 += 32) {
    gll16(Ag, Al);
    gll16(Ag + rowadv, Al + 1024);
    gll16(Bg, Bl);
    gll16(Bg + rowadv, Bl + 1024);
    Ag += 64; Bg += 64;
    __syncthreads();
    bf16x8 af[4], bq[4];
#pragma unroll
    for (int i = 0; i < 4; ++i) {
      af[i] = *(const bf16x8*)&As[(wr * 64 + i * 16 + (l & 15)) * 32 + (l >> 4) * 8];
      bq[i] = *(const bf16x8*)&Bs[(wc * 64 + i * 16 + (l & 15)) * 32 + (l >> 4) * 8];
    }
#pragma unroll
    for (int mi = 0; mi < 4; ++mi)
#pragma unroll
      for (int ni = 0; ni < 4; ++ni)
        acc[mi][ni] = __builtin_amdgcn_mfma_f32_16x16x32_bf16(af[mi], bq[ni], acc[mi][ni], 0, 0, 0);
    __syncthreads();
  }
  float* Cs = C + sl * pstr;
  const int r0 = (l >> 4) * 4, c0 = l & 15;
#pragma unroll
  for (int mi = 0; mi < 4; ++mi)
#pragma unroll
    for (int ni = 0; ni < 4; ++ni)
#pragma unroll
      for (int r = 0; r < 4; ++r)
        Cs[(size_t)(m0 + wr * 64 + mi * 16 + r0 + r) * N + (n0 + wc * 64 + ni * 16 + c0)] =
            acc[mi][ni][r];
}

// ---------------- big GEMM: 256(M) x 128(N) tile, FULL-K, 8 waves (4Mx2N,
// 64x64/wave). LDS 96KB = 4 pages x 24KB. R14-proven (72.6us, 946 TF).
template <int BF16OUT>
__global__ __launch_bounds__(512) void gemm_mn(const u16* __restrict__ A,
                                               const u16* __restrict__ Bt,
                                               void* __restrict__ Cout,
                                               int M, int N, int K) {
  extern __shared__ __align__(16) char lds[];
  int bid = blockIdx.x;
  const int cpx = gridDim.x >> 3;
  bid = (bid & 7) * cpx + (bid >> 3);
  const int nbn = N >> 7;
  const int bm = bid / nbn, bn = bid % nbn;
  const int m0 = bm << 8, n0 = bn << 7;
  const int t = threadIdx.x, w = t >> 6, l = t & 63;
  const int wr = w >> 1, wc = w & 1;            // waves 4(M) x 2(N); per-wave 64x64
  const int lr = l & 15, lg = l >> 4;

  const int sR = t >> 3, slot = t & 7;
  const int su = slot ^ (sR & 7);
  const int d1 = sR * 128 + slot * 16;
  const u16* Ag = A + (size_t)(m0 + 2 * sR + (su >> 2)) * K + (su & 3) * 8;
  const u16* Bg = Bt + (size_t)(n0 + 2 * sR + (su >> 2)) * K + (su & 3) * 8;
  const size_t r128 = (size_t)128 * K;

  f32x4 acc[4][4] = {};
  const int NPH = K >> 5;   // 128 for K=4096

  auto stage = [&](int ph) {
    const int kofs = ph * 32;
    char* pb = lds + (ph & 3) * 24576;
    gll16(Ag + kofs, pb + d1);                 // A m 0..127
    gll16(Ag + r128 + kofs, pb + 8192 + d1);   // A m 128..255
    gll16(Bg + kofs, pb + 16384 + d1);         // B n 0..127
  };
  stage(0);
  stage(1);
  stage(2);

  const int sfrag = ((lr & 1) << 2) | lg;
  const int swz = (sfrag ^ ((lr >> 1) & 7)) << 4;
  const int aoff = (wr * 32 + (lr >> 1)) * 128 + swz;
  const int boff = 16384 + (wc * 32 + (lr >> 1)) * 128 + swz;

  bf16x8 a[4], b[4];
  auto read_frags = [&](int ph) {
    const char* base = lds + (ph & 3) * 24576;
#pragma unroll
    for (int mf = 0; mf < 4; ++mf) a[mf] = *(const bf16x8*)(base + aoff + mf * 1024);
#pragma unroll
    for (int nf = 0; nf < 4; ++nf) b[nf] = *(const bf16x8*)(base + boff + nf * 1024);
  };
  auto mfma16 = [&]() {
    __builtin_amdgcn_s_setprio(1);
#pragma unroll
    for (int mf = 0; mf < 4; ++mf)
#pragma unroll
      for (int nf = 0; nf < 4; ++nf)
        acc[mf][nf] = __builtin_amdgcn_mfma_f32_16x16x32_bf16(a[mf], b[nf], acc[mf][nf], 0, 0, 0);
    __builtin_amdgcn_s_setprio(0);
    asm volatile("" ::: "memory");
  };

#define GSYNC(NW) __builtin_amdgcn_sched_barrier(0); \
  asm volatile("s_waitcnt vmcnt(" #NW ")" ::: "memory"); \
  __builtin_amdgcn_s_barrier(); \
  __builtin_amdgcn_sched_barrier(0);

  GSYNC(6)
  read_frags(0);

  for (int ph = 0; ph < NPH - 3; ++ph) {
    __builtin_amdgcn_sched_barrier(0);
    stage(ph + 3);
    mfma16();
    GSYNC(6)
    read_frags(ph + 1);
  }
  __builtin_amdgcn_sched_barrier(0);
  mfma16();
  GSYNC(3)
  read_frags(NPH - 2);
  __builtin_amdgcn_sched_barrier(0);
  mfma16();
  GSYNC(0)
  read_frags(NPH - 1);
  __builtin_amdgcn_sched_barrier(0);
  mfma16();
#undef GSYNC

#pragma unroll
  for (int mf = 0; mf < 4; ++mf)
#pragma unroll
    for (int nf = 0; nf < 4; ++nf)
#pragma unroll
      for (int rr = 0; rr < 4; ++rr) {
        const size_t cidx = (size_t)(m0 + wr * 64 + mf * 16 + lg * 4 + rr) * N +
                            (n0 + wc * 64 + nf * 16 + lr);
        if (BF16OUT)
          ((u16*)Cout)[cidx] = bfc(acc[mf][nf][rr]);
        else
          ((float*)Cout)[cidx] = acc[mf][nf][rr];
      }
}

// ---------------- flash attention: 512 threads (8 waves), 128 Q-rows x 2 heads
// per block (shared KV staging amortized 4x vs 1-head/64-row), fused Q
// RMSNorm+RoPE, swapped-QK^T, static-max softmax (P = exp2(S)).
__global__ __launch_bounds__(512) void attn_fwd(const u16* __restrict__ Qp,
                                                const u16* __restrict__ Kb,
                                                const u16* __restrict__ VT,
                                                const float* __restrict__ nw,
                                                const float* __restrict__ cosT,
                                                const float* __restrict__ sinT,
                                                u16* __restrict__ O) {
  const int hp = blockIdx.x & 31;                        // head pair
  const int qblk = (S_LEN / 128 - 1) - (blockIdx.x >> 5);  // big blocks first
  const int h0 = hp << 1;
  const int kvh = h0 >> 4;
  __shared__ __align__(16) char KV[2 * 16384];  // page: K 8KB | V 8KB
  const int tid = threadIdx.x;
  const int w = tid >> 6, l = tid & 63;
  const int wh = w >> 2, w4 = w & 3;            // q-half, 16-row group
  const int lr = l & 15, lg = l >> 4;

  // staging: each of 8 waves loads 8 K rows + 8 V rows per tile
  const int srow = w * 8 + (l >> 3);
  const int s0 = (l & 7) ^ (srow & 7);                          // inverse bank swizzle
  const int sv = (s0 & 4) | ((s0 & 1) << 1) | ((s0 & 2) >> 1);  // + pi for V packs
  const char* Kg = (const char*)Kb + kvh * 128 + (size_t)srow * 512 + s0 * 16;
  const char* Vg = (const char*)VT + (size_t)(kvh * 64 + srow) * (S_LEN * 2) + sv * 16;
  const int wofs = w * 1024;

  auto stage = [&](int page) {
    char* pb = KV + page * 16384 + wofs;
    gll16(Kg, pb);
    gll16(Vg, pb + 8192);
    Kg += 64 * 512;
    Vg += 128;
  };

  const int qrow = qblk * 128 + wh * 64 + w4 * 16 + lr;

  // ---- fused RMSNorm + RoPE for this lane's Q fragments (both heads) ----
  float cv[8], sn_[8], nv[16];
#pragma unroll
  for (int jj = 0; jj < 4; ++jj) {
    cv[jj]      = cosT[(size_t)qrow * 32 + lg * 4 + jj];
    sn_[jj]     = sinT[(size_t)qrow * 32 + lg * 4 + jj];
    cv[4 + jj]  = cosT[(size_t)qrow * 32 + 16 + lg * 4 + jj];
    sn_[4 + jj] = sinT[(size_t)qrow * 32 + 16 + lg * 4 + jj];
  }
#pragma unroll
  for (int j = 0; j < 8; ++j) {
    nv[j]     = nw[lg * 8 + j];
    nv[8 + j] = nw[32 + lg * 8 + j];
  }
  const float QSCALE = 0.125f * 1.44269504088896340736f;

  auto mkq = [&](int h, bf16x8* qf) {
    const size_t qoff = (size_t)qrow * DMODEL + h * HD + lg * 8;
    u16x8 r0 = *(const u16x8*)&Qp[qoff];
    u16x8 r1 = *(const u16x8*)&Qp[qoff + 32];
    float v[16];
    float sq = 0.f;
#pragma unroll
    for (int j = 0; j < 8; ++j) {
      v[j] = bf2f(r0[j]);
      v[8 + j] = bf2f(r1[j]);
      sq = fmaf(v[j], v[j], sq);
      sq = fmaf(v[8 + j], v[8 + j], sq);
    }
    sq += __shfl_xor(sq, 16, 64);
    sq += __shfl_xor(sq, 32, 64);
    const float rr = rsqrtf(sq * (1.f / 64.f) + 1e-5f) * QSCALE;
    u32x4 w0, w1;
#pragma unroll
    for (int jj = 0; jj < 4; ++jj) {
      const float re0 = v[2 * jj] * nv[2 * jj] * rr;
      const float im0 = v[2 * jj + 1] * nv[2 * jj + 1] * rr;
      w0[jj] = pk2(re0 * cv[jj] - im0 * sn_[jj], re0 * sn_[jj] + im0 * cv[jj]);
      const float re1 = v[8 + 2 * jj] * nv[8 + 2 * jj] * rr;
      const float im1 = v[8 + 2 * jj + 1] * nv[8 + 2 * jj + 1] * rr;
      w1[jj] = pk2(re1 * cv[4 + jj] - im1 * sn_[4 + jj], re1 * sn_[4 + jj] + im1 * cv[4 + jj]);
    }
    qf[0] = __builtin_bit_cast(bf16x8, w0);
    qf[1] = __builtin_bit_cast(bf16x8, w1);
  };
  bf16x8 qfA[2], qfB[2];
  mkq(h0, qfA);
  mkq(h0 + 1, qfB);

  f32x4 oA[4] = {}, oB[4] = {};
  float lrowA = 0.f, lrowB = 0.f;
  const int abase = (l & 48) | ((l >> 2) & 12);  // lane holding q = lg*4+r is abase+r

  const int xr = lr & 7;
  const int kb0 = lr * 128 + ((lg ^ xr) << 4);
  const int kb1 = lr * 128 + (((4 + lg) ^ xr) << 4);
  const int vb0 = 8192 + kb0;
  const int vb1 = 8192 + kb1;

  auto proc = [&](const char* page, const bf16x8* qf, f32x4* o, float& lrow, bool diag,
                  int t) {
    f32x4 sf[4] = {};
    __builtin_amdgcn_s_setprio(1);
#pragma unroll
    for (int ni = 0; ni < 4; ++ni) {
      bf16x8 kf0 = *(const bf16x8*)(page + kb0 + ni * 2048);
      bf16x8 kf1 = *(const bf16x8*)(page + kb1 + ni * 2048);
      sf[ni] = __builtin_amdgcn_mfma_f32_16x16x32_bf16(kf0, qf[0], sf[ni], 0, 0, 0);
      sf[ni] = __builtin_amdgcn_mfma_f32_16x16x32_bf16(kf1, qf[1], sf[ni], 0, 0, 0);
    }
    __builtin_amdgcn_s_setprio(0);
    if (diag) {
      const int kvb = t * 64 + lg * 4;
#pragma unroll
      for (int ni = 0; ni < 4; ++ni)
#pragma unroll
        for (int r = 0; r < 4; ++r)
          if (kvb + ni * 16 + r > qrow) sf[ni][r] = -1e30f;
    }
    float p[4][4];
    float r4[4];
#pragma unroll
    for (int ni = 0; ni < 4; ++ni) {
#pragma unroll
      for (int r = 0; r < 4; ++r) p[ni][r] = ex2(sf[ni][r]);
      r4[ni] = (p[ni][0] + p[ni][1]) + (p[ni][2] + p[ni][3]);
    }
    float rs = (r4[0] + r4[1]) + (r4[2] + r4[3]);
    rs += __shfl_xor(rs, 16, 64);
    rs += __shfl_xor(rs, 32, 64);
    lrow += rs;

    const bool odd = (lg & 1);
#pragma unroll
    for (int kk = 0; kk < 2; ++kk) {
      const int nA = 2 * kk, nB = 2 * kk + 1;
      const u32 cA0 = pk2(p[nA][0], p[nA][1]), cA1 = pk2(p[nA][2], p[nA][3]);
      const u32 cB0 = pk2(p[nB][0], p[nB][1]), cB1 = pk2(p[nB][2], p[nB][3]);
      const u32 cS0 = odd ? cB0 : cA0, cS1 = odd ? cB1 : cA1;
      const u32 cP0 = odd ? cA0 : cB0, cP1 = odd ? cA1 : cB1;
      const u32 rP0 = (u32)__shfl_xor((int)cP0, 16, 64);
      const u32 rP1 = (u32)__shfl_xor((int)cP1, 16, 64);
      u32x4 wv;
      wv[0] = odd ? rP0 : cS0;
      wv[1] = odd ? rP1 : cS1;
      wv[2] = odd ? cS0 : rP0;
      wv[3] = odd ? cS1 : rP1;
      const bf16x8 pa = __builtin_bit_cast(bf16x8, wv);
      const int vb = kk ? vb1 : vb0;
      __builtin_amdgcn_s_setprio(1);
#pragma unroll
      for (int ni = 0; ni < 4; ++ni) {
        bf16x8 vf = *(const bf16x8*)(page + vb + ni * 2048);
        o[ni] = __builtin_amdgcn_mfma_f32_16x16x32_bf16(pa, vf, o[ni], 0, 0, 0);
      }
      __builtin_amdgcn_s_setprio(0);
    }
  };

  stage(0);

  const int nt = 2 * qblk + 2;           // tiles covering rows [0, qblk*128+128)
  const int dstart = 2 * qblk + wh;      // this wave-half's diagonal tile

  for (int t = 0; t < nt; ++t) {
    __builtin_amdgcn_sched_barrier(0);
    asm volatile("s_waitcnt vmcnt(0)" ::: "memory");
    __builtin_amdgcn_s_barrier();
    __builtin_amdgcn_sched_barrier(0);
    if (t + 1 < nt) stage((t + 1) & 1);
    const char* page = KV + (t & 1) * 16384;
    const bool diag = (t >= dstart);     // wave-uniform
    proc(page, qfA, oA, lrowA, diag, t);
    proc(page, qfB, oB, lrowB, diag, t);
  }

  auto fin = [&](const f32x4* o, float lrow, int h) {
    const f32x4 lv = {__shfl(lrow, abase + 0, 64), __shfl(lrow, abase + 1, 64),
                      __shfl(lrow, abase + 2, 64), __shfl(lrow, abase + 3, 64)};
    const f32x4 il = {1.f / lv[0], 1.f / lv[1], 1.f / lv[2], 1.f / lv[3]};
#pragma unroll
    for (int ni = 0; ni < 4; ++ni)
#pragma unroll
      for (int r = 0; r < 4; ++r) {
        const size_t orow = (size_t)(qblk * 128 + wh * 64 + w4 * 16 + lg * 4 + r);
        O[orow * DMODEL + h * HD + ni * 16 + lr] = f2bf(o[ni][r] * il[r]);
      }
  };
  fin(oA, lrowA, h0);
  fin(oB, lrowB, h0 + 1);
}

// ---------------- launcher ----------------
extern "C" void kernel_launch(void* const* d_in, const int* in_sizes, int n_in,
                              void* d_out, int out_size, void* d_ws, size_t ws_size,
                              hipStream_t stream) {
  const float* x   = (const float*)d_in[0];
  const float* wq  = (const float*)d_in[1];
  const float* wk  = (const float*)d_in[2];
  const float* wv  = (const float*)d_in[3];
  const float* wo  = (const float*)d_in[4];
  const float* qnw = (const float*)d_in[5];
  const float* knw = (const float*)d_in[6];
  const float* fc  = (const float*)d_in[7];
  const float* fs  = (const float*)d_in[8];
  float* out = (float*)d_out;

  char* ws = (char*)d_ws;
  size_t off = 0;
  auto alloc = [&](size_t bytes) {
    char* p = ws + off;
    off += (bytes + 255) & ~(size_t)255;
    return p;
  };
  const size_t KVP = (size_t)S_LEN * 512;   // one KV partial slice (elems)
  u16*   xb    = (u16*)alloc((size_t)S_LEN * DMODEL * 2);
  u16*   wqT   = (u16*)alloc((size_t)DMODEL * DMODEL * 2);
  u16*   wkvT  = (u16*)alloc((size_t)512 * DMODEL * 2);
  u16*   woT   = (u16*)alloc((size_t)DMODEL * DMODEL * 2);
  u16*   Pq    = (u16*)alloc((size_t)S_LEN * DMODEL * 2);
  float* KVf   = (float*)alloc(KVP * 4 * 4);   // 4 fp32 partial slices
  u16*   Kn    = (u16*)alloc((size_t)S_LEN * 256 * 2);
  u16*   VTb   = (u16*)alloc((size_t)256 * S_LEN * 2);
  u16*   Ob    = (u16*)alloc((size_t)S_LEN * DMODEL * 2);

  hipFuncSetAttribute((const void*)gemm_mn<1>, hipFuncAttributeMaxDynamicSharedMemorySize, 98304);
  hipFuncSetAttribute((const void*)gemm_mn<0>, hipFuncAttributeMaxDynamicSharedMemorySize, 98304);

  cvt_f32_bf16_v4<<<(S_LEN * DMODEL / 4) / 256, 256, 0, stream>>>(x, xb);
  tconvs<<<(4096 / 32) * (4096 / 32), 256, 0, stream>>>(wq, 4096, wqT, 4096, 4096);
  tconvs<<<(4096 / 32) * (256 / 32), 256, 0, stream>>>(wk, 256, wkvT, 4096, 256);
  tconvs<<<(4096 / 32) * (256 / 32), 256, 0, stream>>>(wv, 256,
      wkvT + (size_t)256 * 4096, 4096, 256);
  tconvs<<<(4096 / 32) * (4096 / 32), 256, 0, stream>>>(wo, 4096, woT, 4096, 4096);

  // Q projection: full-K 256x128 tiles -> 256 blocks, bf16 direct (raw, un-normed)
  gemm_mn<1><<<(2048 / 256) * (4096 / 128), 512, 98304, stream>>>(
      xb, wqT, Pq, 2048, 4096, 4096);
  // KV projection: split-K4 = 256 blocks, fp32 partials
  gemm_kv<<<4 * (2048 / 128) * (512 / 128), 256, 0, stream>>>(
      xb, wkvT, KVf, KVP, 2048, 512, 4096);

  norm_rope_k4<<<(S_LEN * NKV) / 4, 256, 0, stream>>>(KVf, KVP, 512, NKV,
                                                      knw, fc, fs, Kn, 256, 1.0f);
  // V^T: V partials (2048 x 256, row stride 512, 4 slices) -> VT (256 x 2048 bf16)
  tconvs4<<<(2048 / 32) * (256 / 32), 256, 0, stream>>>(KVf + 256, 512, KVP,
                                                        VTb, 2048, 256);

  // attention: 128 q-rows x 2 heads per block; 16 qblk x 32 head-pairs = 512 blocks
  attn_fwd<<<(S_LEN / 128) * (NH / 2), 512, 0, stream>>>(Pq, Kn, VTb, qnw, fc, fs, Ob);

  // out projection: full-K 256x128 tiles -> 256 blocks, fp32 direct to out
  gemm_mn<0><<<(2048 / 256) * (4096 / 128), 512, 98304, stream>>>(
      Ob, woT, out, 2048, 4096, 4096);
}

// Round 19
// 288.118 us; speedup vs baseline: 1.0330x; 1.0330x over previous
//
#include <hip/hip_runtime.h>
#include <hip/hip_bf16.h>

typedef unsigned short u16;
typedef unsigned int   u32;
typedef __attribute__((ext_vector_type(8))) __bf16 bf16x8;
typedef __attribute__((ext_vector_type(4))) float  f32x4;
typedef __attribute__((ext_vector_type(8))) u16    u16x8;
typedef __attribute__((ext_vector_type(4))) u16    u16x4;
typedef __attribute__((ext_vector_type(2))) u32    u32x2;
typedef __attribute__((ext_vector_type(4))) u32    u32x4;

#define S_LEN 2048
#define DMODEL 4096
#define NH 64
#define NKV 4
#define HD 64

__device__ __forceinline__ u16 f2bf(float f) {
  u32 u = __builtin_bit_cast(u32, f);
  u32 r = (u + 0x7FFFu + ((u >> 16) & 1u)) >> 16;
  return (u16)r;
}
__device__ __forceinline__ u16 bfc(float f) {
  return __builtin_bit_cast(u16, (__bf16)f);
}
__device__ __forceinline__ u32 pk2(float lo, float hi) {
  return (u32)bfc(lo) | ((u32)bfc(hi) << 16);
}
__device__ __forceinline__ float bf2f(u16 u) {
  return __builtin_bit_cast(float, (u32)u << 16);
}
__device__ __forceinline__ float ex2(float x) { return __builtin_amdgcn_exp2f(x); }

__device__ __forceinline__ void gll16(const void* g, void* l) {
  __builtin_amdgcn_global_load_lds(
      (__attribute__((address_space(1))) void*)g,
      (__attribute__((address_space(3))) void*)l, 16, 0, 0);
}

// ---------------- elementwise converts ----------------
__global__ __launch_bounds__(256) void cvt_f32_bf16_v4(const float* __restrict__ in,
                                                       u16* __restrict__ out) {
  const int i = blockIdx.x * 256 + threadIdx.x;
  float4 f = ((const float4*)in)[i];
  u16x4 u = { f2bf(f.x), f2bf(f.y), f2bf(f.z), f2bf(f.w) };
  *(u16x4*)&out[(size_t)i * 4] = u;
}

// transpose-convert: in fp32 R x C (row stride istride) -> out bf16 C x R
__global__ __launch_bounds__(256) void tconvs(const float* __restrict__ in, int istride,
                                              u16* __restrict__ out, int R, int C) {
  __shared__ __align__(16) float tile[32][36];
  const int nc = C >> 5;
  const int cb = blockIdx.x % nc, rb = blockIdx.x / nc;
  const int r = threadIdx.x >> 3, c4 = (threadIdx.x & 7) << 2;
  float4 v = *(const float4*)&in[(size_t)(rb * 32 + r) * istride + cb * 32 + c4];
  *(float4*)&tile[r][c4] = v;
  __syncthreads();
  u32x2 pr;
  pr[0] = pk2(tile[c4 + 0][r], tile[c4 + 1][r]);
  pr[1] = pk2(tile[c4 + 2][r], tile[c4 + 3][r]);
  *(u32x2*)&out[(size_t)(cb * 32 + r) * R + rb * 32 + c4] = pr;
}

// dual-source transpose-convert for wk|wv (each 4096 x 256) -> wkvT (512 x 4096)
__global__ __launch_bounds__(256) void tconv_kv(const float* __restrict__ wk,
                                                const float* __restrict__ wv,
                                                u16* __restrict__ outT) {
  const int half = blockIdx.x >> 10;            // 0: wk, 1: wv
  const int b = blockIdx.x & 1023;
  const float* in = half ? wv : wk;
  u16* out = outT + (size_t)half * 256 * 4096;
  __shared__ __align__(16) float tile[32][36];
  const int nc = 256 >> 5;
  const int cb = b % nc, rb = b / nc;
  const int r = threadIdx.x >> 3, c4 = (threadIdx.x & 7) << 2;
  float4 v = *(const float4*)&in[(size_t)(rb * 32 + r) * 256 + cb * 32 + c4];
  *(float4*)&tile[r][c4] = v;
  __syncthreads();
  u32x2 pr;
  pr[0] = pk2(tile[c4 + 0][r], tile[c4 + 1][r]);
  pr[1] = pk2(tile[c4 + 2][r], tile[c4 + 3][r]);
  *(u32x2*)&out[(size_t)(cb * 32 + r) * 4096 + rb * 32 + c4] = pr;
}

// transpose-convert summing 4 fp32 partial slices (slice stride pstr elems)
__global__ __launch_bounds__(256) void tconvs4(const float* __restrict__ in, int istride,
                                               size_t pstr,
                                               u16* __restrict__ out, int R, int C) {
  __shared__ __align__(16) float tile[32][36];
  const int nc = C >> 5;
  const int cb = blockIdx.x % nc, rb = blockIdx.x / nc;
  const int r = threadIdx.x >> 3, c4 = (threadIdx.x & 7) << 2;
  const size_t idx = (size_t)(rb * 32 + r) * istride + cb * 32 + c4;
  float4 v = *(const float4*)&in[idx];
#pragma unroll
  for (int j = 1; j < 4; ++j) {
    float4 u = *(const float4*)&in[idx + j * pstr];
    v.x += u.x; v.y += u.y; v.z += u.z; v.w += u.w;
  }
  *(float4*)&tile[r][c4] = v;
  __syncthreads();
  u32x2 pr;
  pr[0] = pk2(tile[c4 + 0][r], tile[c4 + 1][r]);
  pr[1] = pk2(tile[c4 + 2][r], tile[c4 + 3][r]);
  *(u32x2*)&out[(size_t)(cb * 32 + r) * R + rb * 32 + c4] = pr;
}

// ---------------- RMSNorm + RoPE, fp32 4-partial input (K path) ------------
__global__ __launch_bounds__(256) void norm_rope_k4(const float* __restrict__ in,
                                                    size_t pstr,
                                                    int in_stride, int nheads,
                                                    const float* __restrict__ nw,
                                                    const float* __restrict__ cosT,
                                                    const float* __restrict__ sinT,
                                                    u16* __restrict__ outp, int out_stride,
                                                    float oscale) {
  const int wid = blockIdx.x * 4 + (threadIdx.x >> 6);
  const int l = threadIdx.x & 63;
  const int s = wid / nheads, h = wid - s * nheads;
  const size_t idx = (size_t)s * in_stride + h * 64 + l;
  float v = in[idx];
#pragma unroll
  for (int j = 1; j < 4; ++j) v += in[idx + j * pstr];
  float sq = v * v;
#pragma unroll
  for (int off = 32; off; off >>= 1) sq += __shfl_xor(sq, off, 64);
  const float rr = rsqrtf(sq * (1.f / 64.f) + 1e-5f);
  const float vn = v * rr * nw[l];
  const float p = __shfl_xor(vn, 1, 64);
  const int i2 = l >> 1;
  const float c = cosT[(size_t)s * 32 + i2];
  const float sn = sinT[(size_t)s * 32 + i2];
  const float o = ((l & 1) ? fmaf(p, sn, vn * c) : fmaf(-p, sn, vn * c)) * oscale;
  outp[(size_t)s * out_stride + h * 64 + l] = f2bf(o);
}

// ---------------- KV projection: 128x128 tiles, split-K=4 (256 blocks) --------
__global__ __launch_bounds__(256) void gemm_kv(const u16* __restrict__ A,
                                               const u16* __restrict__ Bt,
                                               float* __restrict__ C, size_t pstr,
                                               int M, int N, int K) {
  __shared__ __align__(16) u16 As[128 * 32];
  __shared__ __align__(16) u16 Bs[128 * 32];
  int bid = blockIdx.x;
  const int cpx = gridDim.x >> 3;
  bid = (bid & 7) * cpx + (bid >> 3);
  const int nbn = N >> 7;
  const int pertile = (M >> 7) * nbn;
  const int sl = bid / pertile;
  const int rem = bid - sl * pertile;
  const int bm = rem / nbn, bn = rem % nbn;
  const int m0 = bm << 7, n0 = bn << 7;
  const int tid = threadIdx.x;
  const int w = tid >> 6, l = tid & 63;
  const int wr = w >> 1, wc = w & 1;
  f32x4 acc[4][4] = {};

  const int Kq = K >> 2;
  const int kbase = sl * Kq;

  const char* Ag = (const char*)A +
      ((size_t)(m0 + w * 32 + (l >> 2)) * K + kbase + (l & 3) * 8) * 2;
  const char* Bg = (const char*)Bt +
      ((size_t)(n0 + w * 32 + (l >> 2)) * K + kbase + (l & 3) * 8) * 2;
  char* Al = (char*)As + (w * 32) * 64;
  char* Bl = (char*)Bs + (w * 32) * 64;
  const size_t rowadv = (size_t)16 * K * 2;

  for (int k0 = 0; k0 < Kq; k0 += 32) {
    gll16(Ag, Al);
    gll16(Ag + rowadv, Al + 1024);
    gll16(Bg, Bl);
    gll16(Bg + rowadv, Bl + 1024);
    Ag += 64; Bg += 64;
    __syncthreads();
    bf16x8 af[4], bq[4];
#pragma unroll
    for (int i = 0; i < 4; ++i) {
      af[i] = *(const bf16x8*)&As[(wr * 64 + i * 16 + (l & 15)) * 32 + (l >> 4) * 8];
      bq[i] = *(const bf16x8*)&Bs[(wc * 64 + i * 16 + (l & 15)) * 32 + (l >> 4) * 8];
    }
#pragma unroll
    for (int mi = 0; mi < 4; ++mi)
#pragma unroll
      for (int ni = 0; ni < 4; ++ni)
        acc[mi][ni] = __builtin_amdgcn_mfma_f32_16x16x32_bf16(af[mi], bq[ni], acc[mi][ni], 0, 0, 0);
    __syncthreads();
  }
  float* Cs = C + sl * pstr;
  const int r0 = (l >> 4) * 4, c0 = l & 15;
#pragma unroll
  for (int mi = 0; mi < 4; ++mi)
#pragma unroll
    for (int ni = 0; ni < 4; ++ni)
#pragma unroll
      for (int r = 0; r < 4; ++r)
        Cs[(size_t)(m0 + wr * 64 + mi * 16 + r0 + r) * N + (n0 + wc * 64 + ni * 16 + c0)] =
            acc[mi][ni][r];
}

// ---------------- big GEMM: 256(M) x 128(N) tile, FULL-K, 8 waves (4Mx2N,
// 64x64/wave). LDS 96KB = 4 pages x 24KB. R14-proven (72.6us, 946 TF).
template <int BF16OUT>
__global__ __launch_bounds__(512) void gemm_mn(const u16* __restrict__ A,
                                               const u16* __restrict__ Bt,
                                               void* __restrict__ Cout,
                                               int M, int N, int K) {
  extern __shared__ __align__(16) char lds[];
  int bid = blockIdx.x;
  const int cpx = gridDim.x >> 3;
  bid = (bid & 7) * cpx + (bid >> 3);
  const int nbn = N >> 7;
  const int bm = bid / nbn, bn = bid % nbn;
  const int m0 = bm << 8, n0 = bn << 7;
  const int t = threadIdx.x, w = t >> 6, l = t & 63;
  const int wr = w >> 1, wc = w & 1;            // waves 4(M) x 2(N); per-wave 64x64
  const int lr = l & 15, lg = l >> 4;

  const int sR = t >> 3, slot = t & 7;
  const int su = slot ^ (sR & 7);
  const int d1 = sR * 128 + slot * 16;
  const u16* Ag = A + (size_t)(m0 + 2 * sR + (su >> 2)) * K + (su & 3) * 8;
  const u16* Bg = Bt + (size_t)(n0 + 2 * sR + (su >> 2)) * K + (su & 3) * 8;
  const size_t r128 = (size_t)128 * K;

  f32x4 acc[4][4] = {};
  const int NPH = K >> 5;   // 128 for K=4096

  auto stage = [&](int ph) {
    const int kofs = ph * 32;
    char* pb = lds + (ph & 3) * 24576;
    gll16(Ag + kofs, pb + d1);                 // A m 0..127
    gll16(Ag + r128 + kofs, pb + 8192 + d1);   // A m 128..255
    gll16(Bg + kofs, pb + 16384 + d1);         // B n 0..127
  };
  stage(0);
  stage(1);
  stage(2);

  const int sfrag = ((lr & 1) << 2) | lg;
  const int swz = (sfrag ^ ((lr >> 1) & 7)) << 4;
  const int aoff = (wr * 32 + (lr >> 1)) * 128 + swz;
  const int boff = 16384 + (wc * 32 + (lr >> 1)) * 128 + swz;

  bf16x8 a[4], b[4];
  auto read_frags = [&](int ph) {
    const char* base = lds + (ph & 3) * 24576;
#pragma unroll
    for (int mf = 0; mf < 4; ++mf) a[mf] = *(const bf16x8*)(base + aoff + mf * 1024);
#pragma unroll
    for (int nf = 0; nf < 4; ++nf) b[nf] = *(const bf16x8*)(base + boff + nf * 1024);
  };
  auto mfma16 = [&]() {
    __builtin_amdgcn_s_setprio(1);
#pragma unroll
    for (int mf = 0; mf < 4; ++mf)
#pragma unroll
      for (int nf = 0; nf < 4; ++nf)
        acc[mf][nf] = __builtin_amdgcn_mfma_f32_16x16x32_bf16(a[mf], b[nf], acc[mf][nf], 0, 0, 0);
    __builtin_amdgcn_s_setprio(0);
    asm volatile("" ::: "memory");
  };

#define GSYNC(NW) __builtin_amdgcn_sched_barrier(0); \
  asm volatile("s_waitcnt vmcnt(" #NW ")" ::: "memory"); \
  __builtin_amdgcn_s_barrier(); \
  __builtin_amdgcn_sched_barrier(0);

  GSYNC(6)
  read_frags(0);

  for (int ph = 0; ph < NPH - 3; ++ph) {
    __builtin_amdgcn_sched_barrier(0);
    stage(ph + 3);
    mfma16();
    GSYNC(6)
    read_frags(ph + 1);
  }
  __builtin_amdgcn_sched_barrier(0);
  mfma16();
  GSYNC(3)
  read_frags(NPH - 2);
  __builtin_amdgcn_sched_barrier(0);
  mfma16();
  GSYNC(0)
  read_frags(NPH - 1);
  __builtin_amdgcn_sched_barrier(0);
  mfma16();
#undef GSYNC

#pragma unroll
  for (int mf = 0; mf < 4; ++mf)
#pragma unroll
    for (int nf = 0; nf < 4; ++nf)
#pragma unroll
      for (int rr = 0; rr < 4; ++rr) {
        const size_t cidx = (size_t)(m0 + wr * 64 + mf * 16 + lg * 4 + rr) * N +
                            (n0 + wc * 64 + nf * 16 + lr);
        if (BF16OUT)
          ((u16*)Cout)[cidx] = bfc(acc[mf][nf][rr]);
        else
          ((float*)Cout)[cidx] = acc[mf][nf][rr];
      }
}

// ---------------- flash attention: 2 Q-heads per block (shared KV staging),
// fused Q RMSNorm+RoPE, swapped-QK^T, static-max softmax (P = exp2(S)),
// DEFERRED row-sum reduction (single cross-lane reduce in epilogue).
__global__ __launch_bounds__(256) void attn_fwd(const u16* __restrict__ Qp,
                                                const u16* __restrict__ Kb,
                                                const u16* __restrict__ VT,
                                                const float* __restrict__ nw,
                                                const float* __restrict__ cosT,
                                                const float* __restrict__ sinT,
                                                u16* __restrict__ O) {
  const int hp = blockIdx.x & 31;                       // head pair
  const int qb = (S_LEN / 64 - 1) - (blockIdx.x >> 5);  // big blocks first
  const int h0 = hp << 1;
  const int kvh = h0 >> 4;
  __shared__ __align__(16) char KV[2 * 16384];  // page: K 8KB | V 8KB
  const int tid = threadIdx.x;
  const int w = tid >> 6, l = tid & 63;
  const int lr = l & 15, lg = l >> 4;

  const int srow = w * 16 + (l >> 3);
  const int s0 = (l & 7) ^ (srow & 7);                          // inverse bank swizzle
  const int sv = (s0 & 4) | ((s0 & 1) << 1) | ((s0 & 2) >> 1);  // + pi for V packs
  const char* Kg = (const char*)Kb + kvh * 128 + (size_t)srow * 512 + s0 * 16;
  const char* Vg = (const char*)VT + (size_t)(kvh * 64 + srow) * (S_LEN * 2) + sv * 16;
  const int wofs = w * 2048;

  auto stage = [&](int page) {
    char* pb = KV + page * 16384 + wofs;
    gll16(Kg, pb);
    gll16(Kg + 8 * 512, pb + 1024);
    gll16(Vg, pb + 8192);
    gll16(Vg + 8 * (S_LEN * 2), pb + 8192 + 1024);
    Kg += 64 * 512;
    Vg += 128;
  };

  const int qrow = qb * 64 + w * 16 + lr;

  // ---- fused RMSNorm + RoPE for this lane's Q fragments (both heads) ----
  float cv[8], sn_[8], nv[16];
#pragma unroll
  for (int jj = 0; jj < 4; ++jj) {
    cv[jj]      = cosT[(size_t)qrow * 32 + lg * 4 + jj];
    sn_[jj]     = sinT[(size_t)qrow * 32 + lg * 4 + jj];
    cv[4 + jj]  = cosT[(size_t)qrow * 32 + 16 + lg * 4 + jj];
    sn_[4 + jj] = sinT[(size_t)qrow * 32 + 16 + lg * 4 + jj];
  }
#pragma unroll
  for (int j = 0; j < 8; ++j) {
    nv[j]     = nw[lg * 8 + j];
    nv[8 + j] = nw[32 + lg * 8 + j];
  }
  const float QSCALE = 0.125f * 1.44269504088896340736f;

  auto mkq = [&](int h, bf16x8* qf) {
    const size_t qoff = (size_t)qrow * DMODEL + h * HD + lg * 8;
    u16x8 r0 = *(const u16x8*)&Qp[qoff];
    u16x8 r1 = *(const u16x8*)&Qp[qoff + 32];
    float v[16];
    float sq = 0.f;
#pragma unroll
    for (int j = 0; j < 8; ++j) {
      v[j] = bf2f(r0[j]);
      v[8 + j] = bf2f(r1[j]);
      sq = fmaf(v[j], v[j], sq);
      sq = fmaf(v[8 + j], v[8 + j], sq);
    }
    sq += __shfl_xor(sq, 16, 64);
    sq += __shfl_xor(sq, 32, 64);
    const float rr = rsqrtf(sq * (1.f / 64.f) + 1e-5f) * QSCALE;
    u32x4 w0, w1;
#pragma unroll
    for (int jj = 0; jj < 4; ++jj) {
      const float re0 = v[2 * jj] * nv[2 * jj] * rr;
      const float im0 = v[2 * jj + 1] * nv[2 * jj + 1] * rr;
      w0[jj] = pk2(re0 * cv[jj] - im0 * sn_[jj], re0 * sn_[jj] + im0 * cv[jj]);
      const float re1 = v[8 + 2 * jj] * nv[8 + 2 * jj] * rr;
      const float im1 = v[8 + 2 * jj + 1] * nv[8 + 2 * jj + 1] * rr;
      w1[jj] = pk2(re1 * cv[4 + jj] - im1 * sn_[4 + jj], re1 * sn_[4 + jj] + im1 * cv[4 + jj]);
    }
    qf[0] = __builtin_bit_cast(bf16x8, w0);
    qf[1] = __builtin_bit_cast(bf16x8, w1);
  };
  bf16x8 qfA[2], qfB[2];
  mkq(h0, qfA);
  mkq(h0 + 1, qfB);

  f32x4 oA[4] = {}, oB[4] = {};
  float lrowA = 0.f, lrowB = 0.f;   // lane-local partial row-sums (reduced at end)
  const int abase = (l & 48) | ((l >> 2) & 12);  // lane holding q = lg*4+r is abase+r

  const int xr = lr & 7;
  const int kb0 = lr * 128 + ((lg ^ xr) << 4);
  const int kb1 = lr * 128 + (((4 + lg) ^ xr) << 4);
  const int vb0 = 8192 + kb0;
  const int vb1 = 8192 + kb1;

  auto proc = [&](const char* page, const bf16x8* qf, f32x4* o, float& lrow, bool diag,
                  int t) {
    f32x4 sf[4] = {};
    __builtin_amdgcn_s_setprio(1);
#pragma unroll
    for (int ni = 0; ni < 4; ++ni) {
      bf16x8 kf0 = *(const bf16x8*)(page + kb0 + ni * 2048);
      bf16x8 kf1 = *(const bf16x8*)(page + kb1 + ni * 2048);
      sf[ni] = __builtin_amdgcn_mfma_f32_16x16x32_bf16(kf0, qf[0], sf[ni], 0, 0, 0);
      sf[ni] = __builtin_amdgcn_mfma_f32_16x16x32_bf16(kf1, qf[1], sf[ni], 0, 0, 0);
    }
    __builtin_amdgcn_s_setprio(0);
    if (diag) {
      const int kvb = t * 64 + lg * 4;
#pragma unroll
      for (int ni = 0; ni < 4; ++ni)
#pragma unroll
        for (int r = 0; r < 4; ++r)
          if (kvb + ni * 16 + r > qrow) sf[ni][r] = -1e30f;
    }
    float p[4][4];
    float r4[4];
#pragma unroll
    for (int ni = 0; ni < 4; ++ni) {
#pragma unroll
      for (int r = 0; r < 4; ++r) p[ni][r] = ex2(sf[ni][r]);
      r4[ni] = (p[ni][0] + p[ni][1]) + (p[ni][2] + p[ni][3]);
    }
    lrow += (r4[0] + r4[1]) + (r4[2] + r4[3]);   // lane-local; cross-lane deferred

    const bool odd = (lg & 1);
#pragma unroll
    for (int kk = 0; kk < 2; ++kk) {
      const int nA = 2 * kk, nB = 2 * kk + 1;
      const u32 cA0 = pk2(p[nA][0], p[nA][1]), cA1 = pk2(p[nA][2], p[nA][3]);
      const u32 cB0 = pk2(p[nB][0], p[nB][1]), cB1 = pk2(p[nB][2], p[nB][3]);
      const u32 cS0 = odd ? cB0 : cA0, cS1 = odd ? cB1 : cA1;
      const u32 cP0 = odd ? cA0 : cB0, cP1 = odd ? cA1 : cB1;
      const u32 rP0 = (u32)__shfl_xor((int)cP0, 16, 64);
      const u32 rP1 = (u32)__shfl_xor((int)cP1, 16, 64);
      u32x4 wv;
      wv[0] = odd ? rP0 : cS0;
      wv[1] = odd ? rP1 : cS1;
      wv[2] = odd ? cS0 : rP0;
      wv[3] = odd ? cS1 : rP1;
      const bf16x8 pa = __builtin_bit_cast(bf16x8, wv);
      const int vb = kk ? vb1 : vb0;
      __builtin_amdgcn_s_setprio(1);
#pragma unroll
      for (int ni = 0; ni < 4; ++ni) {
        bf16x8 vf = *(const bf16x8*)(page + vb + ni * 2048);
        o[ni] = __builtin_amdgcn_mfma_f32_16x16x32_bf16(pa, vf, o[ni], 0, 0, 0);
      }
      __builtin_amdgcn_s_setprio(0);
    }
  };

  stage(0);

  for (int t = 0; t <= qb; ++t) {
    __builtin_amdgcn_sched_barrier(0);
    asm volatile("s_waitcnt vmcnt(0)" ::: "memory");
    __builtin_amdgcn_s_barrier();
    __builtin_amdgcn_sched_barrier(0);
    if (t < qb) stage((t + 1) & 1);
    const char* page = KV + (t & 1) * 16384;
    const bool diag = (t == qb);
    proc(page, qfA, oA, lrowA, diag, t);
    proc(page, qfB, oB, lrowB, diag, t);
  }

  // deferred cross-lane row-sum reduction (once per head)
  lrowA += __shfl_xor(lrowA, 16, 64);
  lrowA += __shfl_xor(lrowA, 32, 64);
  lrowB += __shfl_xor(lrowB, 16, 64);
  lrowB += __shfl_xor(lrowB, 32, 64);

  auto fin = [&](const f32x4* o, float lrow, int h) {
    const f32x4 lv = {__shfl(lrow, abase + 0, 64), __shfl(lrow, abase + 1, 64),
                      __shfl(lrow, abase + 2, 64), __shfl(lrow, abase + 3, 64)};
    const f32x4 il = {1.f / lv[0], 1.f / lv[1], 1.f / lv[2], 1.f / lv[3]};
#pragma unroll
    for (int ni = 0; ni < 4; ++ni)
#pragma unroll
      for (int r = 0; r < 4; ++r) {
        const size_t orow = (size_t)(qb * 64 + w * 16 + lg * 4 + r);
        O[orow * DMODEL + h * HD + ni * 16 + lr] = f2bf(o[ni][r] * il[r]);
      }
  };
  fin(oA, lrowA, h0);
  fin(oB, lrowB, h0 + 1);
}

// ---------------- launcher ----------------
extern "C" void kernel_launch(void* const* d_in, const int* in_sizes, int n_in,
                              void* d_out, int out_size, void* d_ws, size_t ws_size,
                              hipStream_t stream) {
  const float* x   = (const float*)d_in[0];
  const float* wq  = (const float*)d_in[1];
  const float* wk  = (const float*)d_in[2];
  const float* wv  = (const float*)d_in[3];
  const float* wo  = (const float*)d_in[4];
  const float* qnw = (const float*)d_in[5];
  const float* knw = (const float*)d_in[6];
  const float* fc  = (const float*)d_in[7];
  const float* fs  = (const float*)d_in[8];
  float* out = (float*)d_out;

  char* ws = (char*)d_ws;
  size_t off = 0;
  auto alloc = [&](size_t bytes) {
    char* p = ws + off;
    off += (bytes + 255) & ~(size_t)255;
    return p;
  };
  const size_t KVP = (size_t)S_LEN * 512;   // one KV partial slice (elems)
  u16*   xb    = (u16*)alloc((size_t)S_LEN * DMODEL * 2);
  u16*   wqT   = (u16*)alloc((size_t)DMODEL * DMODEL * 2);
  u16*   wkvT  = (u16*)alloc((size_t)512 * DMODEL * 2);
  u16*   woT   = (u16*)alloc((size_t)DMODEL * DMODEL * 2);
  u16*   Pq    = (u16*)alloc((size_t)S_LEN * DMODEL * 2);
  float* KVf   = (float*)alloc(KVP * 4 * 4);   // 4 fp32 partial slices
  u16*   Kn    = (u16*)alloc((size_t)S_LEN * 256 * 2);
  u16*   VTb   = (u16*)alloc((size_t)256 * S_LEN * 2);
  u16*   Ob    = (u16*)alloc((size_t)S_LEN * DMODEL * 2);

  hipFuncSetAttribute((const void*)gemm_mn<1>, hipFuncAttributeMaxDynamicSharedMemorySize, 98304);
  hipFuncSetAttribute((const void*)gemm_mn<0>, hipFuncAttributeMaxDynamicSharedMemorySize, 98304);

  cvt_f32_bf16_v4<<<(S_LEN * DMODEL / 4) / 256, 256, 0, stream>>>(x, xb);
  tconvs<<<(4096 / 32) * (4096 / 32), 256, 0, stream>>>(wq, 4096, wqT, 4096, 4096);
  tconv_kv<<<2048, 256, 0, stream>>>(wk, wv, wkvT);
  tconvs<<<(4096 / 32) * (4096 / 32), 256, 0, stream>>>(wo, 4096, woT, 4096, 4096);

  // Q projection: full-K 256x128 tiles -> 256 blocks, bf16 direct (raw, un-normed)
  gemm_mn<1><<<(2048 / 256) * (4096 / 128), 512, 98304, stream>>>(
      xb, wqT, Pq, 2048, 4096, 4096);
  // KV projection: split-K4 = 256 blocks, fp32 partials
  gemm_kv<<<4 * (2048 / 128) * (512 / 128), 256, 0, stream>>>(
      xb, wkvT, KVf, KVP, 2048, 512, 4096);

  norm_rope_k4<<<(S_LEN * NKV) / 4, 256, 0, stream>>>(KVf, KVP, 512, NKV,
                                                      knw, fc, fs, Kn, 256, 1.0f);
  // V^T: V partials (2048 x 256, row stride 512, 4 slices) -> VT (256 x 2048 bf16)
  tconvs4<<<(2048 / 32) * (256 / 32), 256, 0, stream>>>(KVf + 256, 512, KVP,
                                                        VTb, 2048, 256);

  // attention: 2 heads/block, fused Q norm+rope. 32 qb x 32 head-pairs = 1024 blocks
  attn_fwd<<<(S_LEN / 64) * (NH / 2), 256, 0, stream>>>(Pq, Kn, VTb, qnw, fc, fs, Ob);

  // out projection: full-K 256x128 tiles -> 256 blocks, fp32 direct to out
  gemm_mn<0><<<(2048 / 256) * (4096 / 128), 512, 98304, stream>>>(
      Ob, woT, out, 2048, 4096, 4096);
}